// Round 19
// baseline (165.839 us; speedup 1.0000x reference)
//
#include <hip/hip_runtime.h>
#include <stdint.h>

#define T_TOK 2048
#define HDIM  2048
#define FDIM  1024
#define NEXP  8

#define BM   128
#define BK   64
#define NTHR 256
#define MT_MAX 16                 // 2048 / BM
#define BN1  64
#define BN2  128
#define NT1 (FDIM / BN1)          // 16
#define NT2 (HDIM / BN2)          // 16
#define NK1 (HDIM / BK)           // 32
#define NK2 (FDIM / BK)           // 16
#define GRID2K (NEXP * MT_MAX * NT2)  // 2048 (gemm2)
#define TILE_E 4096               // elems per 64x64 bf16 tile (8 KB)
#define SMEM_BYTES 36864

typedef unsigned short u16;
typedef __attribute__((ext_vector_type(16))) float f32x16;
typedef __attribute__((ext_vector_type(8))) short bf16x8;

__device__ __forceinline__ u16 f2bf(float f) {
  uint32_t u = __float_as_uint(f);
  u += 0x7FFFu + ((u >> 16) & 1u);   // RNE
  return (u16)(u >> 16);
}

__device__ __forceinline__ uint32_t pack2(float lo, float hi) {
  return (uint32_t)f2bf(lo) | ((uint32_t)f2bf(hi) << 16);
}

__device__ __forceinline__ void glds16(const u16* src, u16* dst) {
  __builtin_amdgcn_global_load_lds(
      (const __attribute__((address_space(1))) uint32_t*)src,
      (__attribute__((address_space(3))) uint32_t*)dst, 16, 0, 0);
}

// ---------------------------------------------------------------------------
// Routing (order-invariant y; see R2 notes).
// ---------------------------------------------------------------------------
__global__ void route1_kernel(const float* __restrict__ logits,
                              int* __restrict__ tok_e, float* __restrict__ tok_w,
                              int* __restrict__ counts) {
  __shared__ int lcnt[NEXP];
  const int tid = threadIdx.x;
  const int t = blockIdx.x * 256 + tid;
  if (tid < NEXP) lcnt[tid] = 0;
  __syncthreads();
  float l[NEXP];
#pragma unroll
  for (int e = 0; e < NEXP; ++e) l[e] = logits[t * NEXP + e];
  float m = l[0];
#pragma unroll
  for (int e = 1; e < NEXP; ++e) m = fmaxf(m, l[e]);
  float p[NEXP]; float s = 0.f;
#pragma unroll
  for (int e = 0; e < NEXP; ++e) { p[e] = __expf(l[e] - m); s += p[e]; }
  float inv = 1.f / s;
  int i0 = 0; float p0 = p[0];
#pragma unroll
  for (int e = 1; e < NEXP; ++e) if (p[e] > p0) { p0 = p[e]; i0 = e; }
  int i1 = -1; float p1 = -1.f;
#pragma unroll
  for (int e = 0; e < NEXP; ++e) if (e != i0 && p[e] > p1) { p1 = p[e]; i1 = e; }
  tok_e[t] = i0 | (i1 << 8);
  tok_w[t * 2]     = p0 * inv;
  tok_w[t * 2 + 1] = p1 * inv;
  atomicAdd(&lcnt[i0], 1);
  atomicAdd(&lcnt[i1], 1);
  __syncthreads();
  if (tid < NEXP) atomicAdd(&counts[tid], lcnt[tid]);
}

__global__ void route2_kernel(const int* __restrict__ counts,
                              int* __restrict__ offsets, int* __restrict__ cursor) {
  if (threadIdx.x == 0) {
    int s = 0;
    for (int e = 0; e < NEXP; ++e) { offsets[e] = s; cursor[e] = s; s += counts[e]; }
    offsets[NEXP] = s;
  }
}

__global__ void route3_kernel(const int* __restrict__ tok_e, const float* __restrict__ tok_w,
                              int* __restrict__ cursor,
                              int* __restrict__ token_list, float* __restrict__ slot_w) {
  __shared__ int lcnt[NEXP], lbase[NEXP];
  const int tid = threadIdx.x;
  const int t = blockIdx.x * 256 + tid;
  if (tid < NEXP) lcnt[tid] = 0;
  __syncthreads();
  int ee = tok_e[t];
  int e0 = ee & 255, e1 = ee >> 8;
  int li0 = atomicAdd(&lcnt[e0], 1);
  int li1 = atomicAdd(&lcnt[e1], 1);
  __syncthreads();
  if (tid < NEXP) lbase[tid] = atomicAdd(&cursor[tid], lcnt[tid]);
  __syncthreads();
  int s0 = lbase[e0] + li0;
  int s1 = lbase[e1] + li1;
  token_list[s0] = t; slot_w[s0] = tok_w[t * 2];
  token_list[s1] = t; slot_w[s1] = tok_w[t * 2 + 1];
}

// ---------------------------------------------------------------------------
// Weight conversion, v3: float4 phase-1 loads (4x fewer instrs, 1KB/wave).
// Block = 64 k-rows x 128 cols. Phase 1: thread (c=t&31 -> 4 cols, rr=t>>5 ->
// rows rr*8..+8) reads 8 float4 (two 512B coalesced runs per wave instr),
// packs k-pairs, scalar u32 stores to U[n][33] (4-way, 1.58x, hidden).
// Phase 2 (unchanged from R18): contiguous uint4 LDS reads + coalesced 16B
// blob writes. Blob format identical (gemm readers untouched):
// [kq4][n64][k16], k-half hb at offset (hb^s(n))*8, s(n)=(n>>2)&1.
// ---------------------------------------------------------------------------
__device__ __forceinline__ void wconv2_block(const float* __restrict__ src,  // e-offset applied
                                             u16* __restrict__ dstb,
                                             int C, int NT, int NKT,
                                             int e, int kt, int cb, uint32_t* U) {
  const int t = threadIdx.x;
  {
    const int c  = t & 31;        // col-group of 4 floats
    const int rr = t >> 5;        // 0..7 -> rows rr*8 .. rr*8+7
    const float* base = src + (size_t)(kt * 64 + rr * 8) * C + cb * 128 + c * 4;
    float4 f[8];
#pragma unroll
    for (int q = 0; q < 8; ++q) f[q] = *(const float4*)(base + (size_t)q * C);
    uint32_t* d = &U[(c * 4) * 33 + rr * 4];
#pragma unroll
    for (int i = 0; i < 4; ++i) {
      d[0 * 33 + i] = pack2(f[2 * i].x, f[2 * i + 1].x);
      d[1 * 33 + i] = pack2(f[2 * i].y, f[2 * i + 1].y);
      d[2 * 33 + i] = pack2(f[2 * i].z, f[2 * i + 1].z);
      d[3 * 33 + i] = pack2(f[2 * i].w, f[2 * i + 1].w);
    }
  }
  __syncthreads();
  {
    const int ct2 = t >> 7;        // which 64-col blob tile
    const int jj = t & 127;
    const int nn = jj >> 1;        // 0..63
    const int hb = jj & 1;         // k-half
    const int s = (nn >> 2) & 1;
    const int gct = cb * 2 + ct2;
    u16* tb = dstb + (((size_t)e * NT + gct) * NKT + kt) * TILE_E + nn * 16 + ((hb ^ s) * 8);
    const uint32_t* up = &U[(ct2 * 64 + nn) * 33 + hb * 4];
#pragma unroll
    for (int kq = 0; kq < 4; ++kq) {
      uint4 v = *(const uint4*)(up + kq * 8);
      *(uint4*)(tb + kq * 1024) = v;
    }
  }
}

// ---------------------------------------------------------------------------
// MEGA1: bid<4096: w1/w3 conversion (64x128 tiles); 4096..4352: x cvt.
// (y-zero moved to mega2's tail — y feeds only gemm2.)
// ---------------------------------------------------------------------------
__global__ __launch_bounds__(256, 4)
void mega1_kernel(const float* __restrict__ w1, const float* __restrict__ w3,
                  u16* __restrict__ w1b, u16* __restrict__ w3b,
                  const float4* __restrict__ x, ushort4* __restrict__ xb) {
  __shared__ __align__(16) uint32_t U[128 * 33];   // 16.9 KB
  const int bid = blockIdx.x;
  const int t = threadIdx.x;
  if (bid < 4096) {
    const int m = bid >> 11;            // 0=w1, 1=w3
    const int r = bid & 2047;
    const int e = r >> 8;
    const int rr = r & 255;
    const int kt = rr >> 3;             // 0..31
    const int cb = rr & 7;              // 0..7
    const size_t msz = (size_t)HDIM * FDIM;
    wconv2_block((m ? w3 : w1) + (size_t)e * msz, m ? w3b : w1b,
                 FDIM, 16, 32, e, kt, cb, U);
  } else {
    int i = (bid - 4096) * 256 + t;
#pragma unroll
    for (int r = 0; r < 16; ++r, i += 65536) {
      float4 v = x[i];
      ushort4 o;
      o.x = f2bf(v.x); o.y = f2bf(v.y); o.z = f2bf(v.z); o.w = f2bf(v.w);
      xb[i] = o;
    }
  }
}

// ---------------------------------------------------------------------------
// MEGA2: bid<2048: gemm1 (long pole, dispatched first); 2048..4095: w2 conv
// (backfills); 4096..4351: y zero-fill (feeds gemm2 only).
// gemm1 = proven single-buffer 2-barrier schedule, (256,3)
// (4 waves/EU spills the unified VGPR file — R16: 437us).
// ---------------------------------------------------------------------------
__global__ __launch_bounds__(256, 3)
void mega2_kernel(const float* __restrict__ w2, u16* __restrict__ w2b,
                  const u16* __restrict__ Xb,
                  const u16* __restrict__ w1b, const u16* __restrict__ w3b,
                  const int* __restrict__ token_list,
                  const float* __restrict__ slot_w,
                  const int* __restrict__ counts,
                  const int* __restrict__ offsets,
                  u16* __restrict__ act,
                  float4* __restrict__ y4) {
  __shared__ __align__(16) uint8_t smem[SMEM_BYTES];
  const int bid = blockIdx.x;
  if (bid >= 4096) {
    int i = (bid - 4096) * 256 + threadIdx.x;
    float4 z = {0.f, 0.f, 0.f, 0.f};
#pragma unroll
    for (int r = 0; r < 16; ++r, i += 65536) y4[i] = z;
    return;
  }
  if (bid >= 2048) {
    const int r = bid - 2048;           // 0..2047
    const int e = r >> 8;
    const int rr = r & 255;
    const int kt = rr >> 4;             // 0..15
    const int cb = rr & 15;             // 0..15
    wconv2_block(w2 + (size_t)e * HDIM * FDIM, w2b,
                 HDIM, 32, 16, e, kt, cb, (uint32_t*)smem);
    return;
  }
  const int gb = bid;
  const int e  = gb >> 8;
  const int mt = (gb >> 4) & 15;
  const int nt = gb & 15;
  const int cnt = counts[e];
  if (mt * BM >= cnt) return;
  const int off = offsets[e];
  const int tid  = threadIdx.x;
  const int lane = tid & 63;
  const int wid  = tid >> 6;
  const int wr = wid >> 1;
  const int wc = wid & 1;

  u16* A_lds  = (u16*)smem;              // 16 KB, granule^(row&7)
  u16* B1_lds = (u16*)(smem + 16384);    // 8 KB (blob order)
  u16* B3_lds = (u16*)(smem + 24576);    // 8 KB

  const u16* a_src[4];
#pragma unroll
  for (int i = 0; i < 4; ++i) {
    int row = (wid * 4 + i) * 8 + (lane >> 3);
    int mg = mt * BM + row;
    int mc = (mg < cnt) ? mg : (cnt - 1);
    int tok = token_list[off + mc];
    a_src[i] = Xb + (size_t)tok * HDIM + (((lane & 7) ^ (row & 7)) * 8);
  }
  const u16* b1_src[2];
  const u16* b3_src[2];
  {
    size_t tbase = ((size_t)(e * 16 + nt) * 32) * TILE_E;
#pragma unroll
    for (int i = 0; i < 2; ++i) {
      int c = wid * 2 + i;
      b1_src[i] = w1b + tbase + c * 512 + lane * 8;
      b3_src[i] = w3b + tbase + c * 512 + lane * 8;
    }
  }

  f32x16 accg[2] = {};
  f32x16 accu[2] = {};

#pragma unroll
  for (int i = 0; i < 4; ++i) glds16(a_src[i], &A_lds[(wid * 4 + i) * 512]);
#pragma unroll
  for (int i = 0; i < 2; ++i) {
    glds16(b1_src[i], &B1_lds[(wid * 2 + i) * 512]);
    glds16(b3_src[i], &B3_lds[(wid * 2 + i) * 512]);
  }

#pragma unroll 1
  for (int t = 0; t < NK1; ++t) {
    __syncthreads();
    bf16x8 af[2][4], bg[4], bu[4];
#pragma unroll
    for (int m = 0; m < 2; ++m) {
      int R = wr * 64 + m * 32 + (lane & 31);
#pragma unroll
      for (int kk = 0; kk < 4; ++kk) {
        int gl = kk * 2 + (lane >> 5);
        af[m][kk] = *(const bf16x8*)&A_lds[R * BK + ((gl ^ (R & 7)) * 8)];
      }
    }
    {
      int R = wc * 32 + (lane & 31);
      int base = R * 16 + (((lane >> 5) ^ ((R >> 2) & 1)) * 8);
#pragma unroll
      for (int kk = 0; kk < 4; ++kk) {
        bg[kk] = *(const bf16x8*)&B1_lds[base + kk * 1024];
        bu[kk] = *(const bf16x8*)&B3_lds[base + kk * 1024];
      }
    }
    __syncthreads();
    if (t + 1 < NK1) {
      const size_t ks = (size_t)(t + 1) * BK;
      const size_t kb = (size_t)(t + 1) * TILE_E;
#pragma unroll
      for (int i = 0; i < 4; ++i) glds16(a_src[i] + ks, &A_lds[(wid * 4 + i) * 512]);
#pragma unroll
      for (int i = 0; i < 2; ++i) {
        glds16(b1_src[i] + kb, &B1_lds[(wid * 2 + i) * 512]);
        glds16(b3_src[i] + kb, &B3_lds[(wid * 2 + i) * 512]);
      }
    }
#pragma unroll
    for (int m = 0; m < 2; ++m)
#pragma unroll
      for (int kk = 0; kk < 4; ++kk) {
        accg[m] = __builtin_amdgcn_mfma_f32_32x32x16_bf16(af[m][kk], bg[kk], accg[m], 0, 0, 0);
        accu[m] = __builtin_amdgcn_mfma_f32_32x32x16_bf16(af[m][kk], bu[kk], accu[m], 0, 0, 0);
      }
  }

  const int fcol = nt * BN1 + wc * 32 + (lane & 31);
#pragma unroll
  for (int m = 0; m < 2; ++m) {
    int base = mt * BM + wr * 64 + m * 32 + 4 * (lane >> 5);
#pragma unroll
    for (int reg = 0; reg < 16; ++reg) {
      int mg = base + (reg & 3) + 8 * (reg >> 2);
      if (mg < cnt) {
        int slot = off + mg;
        float wgt = slot_w[slot];
        float g = accg[m][reg];
        float u = accu[m][reg];
        float sv = g / (1.f + __expf(-g));
        act[(size_t)slot * FDIM + fcol] = f2bf(sv * u * wgt);
      }
    }
  }
}

// ---------------------------------------------------------------------------
// GEMM2 (unchanged): y += act @ w2 (blob). BM=128 BN=128 BK=64, wave tile
// 64x64, single-buffer 2-barrier schedule, 3 blocks/CU.
// ---------------------------------------------------------------------------
__global__ __launch_bounds__(NTHR, 3)
void gemm2_kernel(const u16* __restrict__ act,
                  const u16* __restrict__ w2b,   // tiled [e][nt32][kt16][4096]
                  const int* __restrict__ token_list,
                  const int* __restrict__ counts,
                  const int* __restrict__ offsets,
                  float* __restrict__ y) {
  const int bid = blockIdx.x;
  const int e  = bid >> 8;
  const int mt = (bid >> 4) & 15;
  const int nt = bid & 15;
  const int cnt = counts[e];
  if (mt * BM >= cnt) return;
  const int off = offsets[e];
  const int tid  = threadIdx.x;
  const int lane = tid & 63;
  const int wid  = tid >> 6;
  const int wr = wid >> 1;
  const int wc = wid & 1;

  __shared__ u16 A_lds[BM * BK];     // 16 KB
  __shared__ u16 B_lds[BN2 * BK];    // 16 KB (two tiles of 4096)

  const u16* a_src[4];
  const u16* b_src[4];
#pragma unroll
  for (int i = 0; i < 4; ++i) {
    int row = (wid * 4 + i) * 8 + (lane >> 3);
    int mg = mt * BM + row;
    int mc = (mg < cnt) ? mg : (cnt - 1);
    a_src[i] = act + (size_t)(off + mc) * FDIM + (((lane & 7) ^ (row & 7)) * 8);
    int c = wid * 4 + i;
    size_t tbase = ((size_t)(e * 32 + nt * 2 + (c >> 3)) * 16) * TILE_E;
    b_src[i] = w2b + tbase + (c & 7) * 512 + lane * 8;
  }

  f32x16 acc[2][2] = {};

#pragma unroll
  for (int i = 0; i < 4; ++i) {
    glds16(a_src[i], &A_lds[(wid * 4 + i) * 512]);
    glds16(b_src[i], &B_lds[(wid * 4 + i) * 512]);
  }

#pragma unroll 1
  for (int t = 0; t < NK2; ++t) {
    __syncthreads();
    bf16x8 af[2][4], bb[2][4];
#pragma unroll
    for (int m = 0; m < 2; ++m) {
      int R = wr * 64 + m * 32 + (lane & 31);
#pragma unroll
      for (int kk = 0; kk < 4; ++kk) {
        int gl = kk * 2 + (lane >> 5);
        af[m][kk] = *(const bf16x8*)&A_lds[R * BK + ((gl ^ (R & 7)) * 8)];
      }
    }
#pragma unroll
    for (int n = 0; n < 2; ++n) {
      int R = wc * 64 + n * 32 + (lane & 31);
      int base = (R >> 6) * TILE_E + (R & 63) * 16 + (((lane >> 5) ^ ((R >> 2) & 1)) * 8);
#pragma unroll
      for (int kk = 0; kk < 4; ++kk)
        bb[n][kk] = *(const bf16x8*)&B_lds[base + kk * 1024];
    }
    __syncthreads();
    if (t + 1 < NK2) {
      const size_t ks = (size_t)(t + 1) * BK;
      const size_t kb = (size_t)(t + 1) * TILE_E;
#pragma unroll
      for (int i = 0; i < 4; ++i) {
        glds16(a_src[i] + ks, &A_lds[(wid * 4 + i) * 512]);
        glds16(b_src[i] + kb, &B_lds[(wid * 4 + i) * 512]);
      }
    }
#pragma unroll
    for (int kk = 0; kk < 4; ++kk)
#pragma unroll
      for (int m = 0; m < 2; ++m)
#pragma unroll
        for (int n = 0; n < 2; ++n)
          acc[m][n] = __builtin_amdgcn_mfma_f32_32x32x16_bf16(af[m][kk], bb[n][kk], acc[m][n], 0, 0, 0);
  }

#pragma unroll
  for (int m = 0; m < 2; ++m) {
    int base = mt * BM + wr * 64 + m * 32 + 4 * (lane >> 5);
#pragma unroll
    for (int reg = 0; reg < 16; ++reg) {
      int mg = base + (reg & 3) + 8 * (reg >> 2);
      if (mg < cnt) {
        int slot = off + mg;
        int tok = token_list[slot];
#pragma unroll
        for (int n = 0; n < 2; ++n) {
          int hcol = nt * BN2 + wc * 64 + n * 32 + (lane & 31);
          unsafeAtomicAdd(y + (size_t)tok * HDIM + hcol, acc[m][n][reg]);
        }
      }
    }
  }
}

// ---------------------------------------------------------------------------
extern "C" void kernel_launch(void* const* d_in, const int* in_sizes, int n_in,
                              void* d_out, int out_size, void* d_ws, size_t ws_size,
                              hipStream_t stream) {
  (void)in_sizes; (void)n_in; (void)out_size; (void)ws_size;
  const float* hs     = (const float*)d_in[0];
  const float* logits = (const float*)d_in[1];
  const float* w1     = (const float*)d_in[2];
  const float* w3     = (const float*)d_in[3];
  const float* w2     = (const float*)d_in[4];
  float* y = (float*)d_out;

  uint8_t* ws = (uint8_t*)d_ws;
  int*   token_list = (int*)(ws);
  float* slot_w     = (float*)(ws + (16 << 10));
  int*   counts     = (int*)(ws + (32 << 10));
  int*   offsets    = (int*)(ws + (32 << 10) + 128);
  int*   cursor     = (int*)(ws + (32 << 10) + 256);
  int*   tok_e      = (int*)(ws + (33 << 10));
  float* tok_w      = (float*)(ws + (42 << 10));
  const size_t MB = 1 << 20;
  u16*   Xb  = (u16*)(ws + (64 << 10));                 // 8 MB
  u16*   act = (u16*)(ws + (64 << 10) + 8 * MB);        // 8 MB
  u16*   w1b = (u16*)(ws + (64 << 10) + 16 * MB);       // 32 MB tiled
  u16*   w3b = (u16*)(ws + (64 << 10) + 48 * MB);       // 32 MB tiled
  u16*   w2b = (u16*)(ws + (64 << 10) + 80 * MB);       // 32 MB tiled

  hipMemsetAsync(counts, 0, NEXP * sizeof(int), stream);
  route1_kernel<<<T_TOK / 256, 256, 0, stream>>>(logits, tok_e, tok_w, counts);
  route2_kernel<<<1, 64, 0, stream>>>(counts, offsets, cursor);
  route3_kernel<<<T_TOK / 256, 256, 0, stream>>>(tok_e, tok_w, cursor, token_list, slot_w);
  mega1_kernel<<<4352, 256, 0, stream>>>(w1, w3, w1b, w3b,
                                         (const float4*)hs, (ushort4*)Xb);
  mega2_kernel<<<4352, 256, 0, stream>>>(w2, w2b, Xb, w1b, w3b,
                                         token_list, slot_w, counts, offsets, act, (float4*)y);
  gemm2_kernel<<<GRID2K, NTHR, 0, stream>>>(act, w2b, token_list, counts, offsets, y);
}

// Round 20
// 163.090 us; speedup vs baseline: 1.0169x; 1.0169x over previous
//
#include <hip/hip_runtime.h>
#include <stdint.h>

#define T_TOK 2048
#define HDIM  2048
#define FDIM  1024
#define NEXP  8

#define BM   128
#define BK   64
#define NTHR 256
#define MT_MAX 16                 // 2048 / BM
#define BN1  64
#define BN2  128
#define NT1 (FDIM / BN1)          // 16
#define NT2 (HDIM / BN2)          // 16
#define NK1 (HDIM / BK)           // 32
#define NK2 (FDIM / BK)           // 16
#define GRID2K (NEXP * MT_MAX * NT2)  // 2048 (gemm2)
#define TILE_E 4096               // elems per 64x64 bf16 tile (8 KB)
#define SMEM_BYTES 36864

typedef unsigned short u16;
typedef __attribute__((ext_vector_type(16))) float f32x16;
typedef __attribute__((ext_vector_type(8))) short bf16x8;

__device__ __forceinline__ u16 f2bf(float f) {
  uint32_t u = __float_as_uint(f);
  u += 0x7FFFu + ((u >> 16) & 1u);   // RNE
  return (u16)(u >> 16);
}

__device__ __forceinline__ uint32_t pack2(float lo, float hi) {
  return (uint32_t)f2bf(lo) | ((uint32_t)f2bf(hi) << 16);
}

__device__ __forceinline__ void glds16(const u16* src, u16* dst) {
  __builtin_amdgcn_global_load_lds(
      (const __attribute__((address_space(1))) uint32_t*)src,
      (__attribute__((address_space(3))) uint32_t*)dst, 16, 0, 0);
}

// ---------------------------------------------------------------------------
// Routing (order-invariant y; see R2 notes).
// ---------------------------------------------------------------------------
__global__ void route1_kernel(const float* __restrict__ logits,
                              int* __restrict__ tok_e, float* __restrict__ tok_w,
                              int* __restrict__ counts) {
  __shared__ int lcnt[NEXP];
  const int tid = threadIdx.x;
  const int t = blockIdx.x * 256 + tid;
  if (tid < NEXP) lcnt[tid] = 0;
  __syncthreads();
  float l[NEXP];
#pragma unroll
  for (int e = 0; e < NEXP; ++e) l[e] = logits[t * NEXP + e];
  float m = l[0];
#pragma unroll
  for (int e = 1; e < NEXP; ++e) m = fmaxf(m, l[e]);
  float p[NEXP]; float s = 0.f;
#pragma unroll
  for (int e = 0; e < NEXP; ++e) { p[e] = __expf(l[e] - m); s += p[e]; }
  float inv = 1.f / s;
  int i0 = 0; float p0 = p[0];
#pragma unroll
  for (int e = 1; e < NEXP; ++e) if (p[e] > p0) { p0 = p[e]; i0 = e; }
  int i1 = -1; float p1 = -1.f;
#pragma unroll
  for (int e = 0; e < NEXP; ++e) if (e != i0 && p[e] > p1) { p1 = p[e]; i1 = e; }
  tok_e[t] = i0 | (i1 << 8);
  tok_w[t * 2]     = p0 * inv;
  tok_w[t * 2 + 1] = p1 * inv;
  atomicAdd(&lcnt[i0], 1);
  atomicAdd(&lcnt[i1], 1);
  __syncthreads();
  if (tid < NEXP) atomicAdd(&counts[tid], lcnt[tid]);
}

__global__ void route2_kernel(const int* __restrict__ counts,
                              int* __restrict__ offsets, int* __restrict__ cursor) {
  if (threadIdx.x == 0) {
    int s = 0;
    for (int e = 0; e < NEXP; ++e) { offsets[e] = s; cursor[e] = s; s += counts[e]; }
    offsets[NEXP] = s;
  }
}

__global__ void route3_kernel(const int* __restrict__ tok_e, const float* __restrict__ tok_w,
                              int* __restrict__ cursor,
                              int* __restrict__ token_list, float* __restrict__ slot_w) {
  __shared__ int lcnt[NEXP], lbase[NEXP];
  const int tid = threadIdx.x;
  const int t = blockIdx.x * 256 + tid;
  if (tid < NEXP) lcnt[tid] = 0;
  __syncthreads();
  int ee = tok_e[t];
  int e0 = ee & 255, e1 = ee >> 8;
  int li0 = atomicAdd(&lcnt[e0], 1);
  int li1 = atomicAdd(&lcnt[e1], 1);
  __syncthreads();
  if (tid < NEXP) lbase[tid] = atomicAdd(&cursor[tid], lcnt[tid]);
  __syncthreads();
  int s0 = lbase[e0] + li0;
  int s1 = lbase[e1] + li1;
  token_list[s0] = t; slot_w[s0] = tok_w[t * 2];
  token_list[s1] = t; slot_w[s1] = tok_w[t * 2 + 1];
}

// ---------------------------------------------------------------------------
// Weight conversion (R18-proven conflict-free variant). Block = 64k x 128n.
// Phase 1: thread owns col n=t&127, rows [half*32, half*32+32) (half=t>>7);
//   32 scalar loads (wave rows 256B-coalesced), pack 16 k-pair u32, store as
//   4x uint4 to U[n][33-pad] (n-stride 1 -> bank-rotating, conflict-free).
// Phase 2: contiguous uint4 LDS reads (2-way free) + coalesced 16B blob
//   writes. Blob format: [kq4][n64][k16], k-half hb at (hb^s(n))*8,
//   s(n)=(n>>2)&1 (gemm readers unchanged).
// ---------------------------------------------------------------------------
__device__ __forceinline__ void wconv2_block(const float* __restrict__ src,  // e-offset applied
                                             u16* __restrict__ dstb,
                                             int C, int NT, int NKT,
                                             int e, int kt, int cb, uint32_t* U) {
  const int t = threadIdx.x;
  {
    const int n = t & 127;
    const int half = t >> 7;
    const float* col0 = src + (size_t)(kt * 64 + half * 32) * C + cb * 128 + n;
    uint32_t pk[16];
#pragma unroll
    for (int q = 0; q < 16; ++q) {
      float a = col0[(size_t)(2 * q) * C];
      float b = col0[(size_t)(2 * q + 1) * C];
      pk[q] = pack2(a, b);
    }
    uint32_t* d = &U[n * 33 + half * 16];
#pragma unroll
    for (int q4 = 0; q4 < 4; ++q4)
      *(uint4*)(d + q4 * 4) = make_uint4(pk[q4 * 4], pk[q4 * 4 + 1], pk[q4 * 4 + 2], pk[q4 * 4 + 3]);
  }
  __syncthreads();
  {
    const int ct2 = t >> 7;        // which 64-col blob tile
    const int jj = t & 127;
    const int nn = jj >> 1;        // 0..63
    const int hb = jj & 1;         // k-half
    const int s = (nn >> 2) & 1;
    const int gct = cb * 2 + ct2;
    u16* tb = dstb + (((size_t)e * NT + gct) * NKT + kt) * TILE_E + nn * 16 + ((hb ^ s) * 8);
    const uint32_t* up = &U[(ct2 * 64 + nn) * 33 + hb * 4];
#pragma unroll
    for (int kq = 0; kq < 4; ++kq) {
      uint4 v = *(const uint4*)(up + kq * 8);
      *(uint4*)(tb + kq * 1024) = v;
    }
  }
}

// ---------------------------------------------------------------------------
// MEGA1: bid<4096: w1/w3 conversion (64x128 tiles); 4096..4352: x cvt.
// (y-zero lives in mega2's tail — overlapped under gemm1.)
// ---------------------------------------------------------------------------
__global__ __launch_bounds__(256, 4)
void mega1_kernel(const float* __restrict__ w1, const float* __restrict__ w3,
                  u16* __restrict__ w1b, u16* __restrict__ w3b,
                  const float4* __restrict__ x, ushort4* __restrict__ xb) {
  __shared__ __align__(16) uint32_t U[128 * 33];   // 16.9 KB
  const int bid = blockIdx.x;
  const int t = threadIdx.x;
  if (bid < 4096) {
    const int m = bid >> 11;            // 0=w1, 1=w3
    const int r = bid & 2047;
    const int e = r >> 8;
    const int rr = r & 255;
    const int kt = rr >> 3;             // 0..31
    const int cb = rr & 7;              // 0..7
    const size_t msz = (size_t)HDIM * FDIM;
    wconv2_block((m ? w3 : w1) + (size_t)e * msz, m ? w3b : w1b,
                 FDIM, 16, 32, e, kt, cb, U);
  } else {
    int i = (bid - 4096) * 256 + t;
#pragma unroll
    for (int r = 0; r < 16; ++r, i += 65536) {
      float4 v = x[i];
      ushort4 o;
      o.x = f2bf(v.x); o.y = f2bf(v.y); o.z = f2bf(v.z); o.w = f2bf(v.w);
      xb[i] = o;
    }
  }
}

// ---------------------------------------------------------------------------
// MEGA2: bid<2048: gemm1 (long pole, dispatched first); 2048..4095: w2 conv
// (backfills); 4096..4351: y zero-fill (feeds gemm2 only; rides under gemm1).
// gemm1 = proven single-buffer 2-barrier schedule, (256,3)
// (4 waves/EU spills the unified VGPR file — R16: 437us).
// ---------------------------------------------------------------------------
__global__ __launch_bounds__(256, 3)
void mega2_kernel(const float* __restrict__ w2, u16* __restrict__ w2b,
                  const u16* __restrict__ Xb,
                  const u16* __restrict__ w1b, const u16* __restrict__ w3b,
                  const int* __restrict__ token_list,
                  const float* __restrict__ slot_w,
                  const int* __restrict__ counts,
                  const int* __restrict__ offsets,
                  u16* __restrict__ act,
                  float4* __restrict__ y4) {
  __shared__ __align__(16) uint8_t smem[SMEM_BYTES];
  const int bid = blockIdx.x;
  if (bid >= 4096) {
    int i = (bid - 4096) * 256 + threadIdx.x;
    float4 z = {0.f, 0.f, 0.f, 0.f};
#pragma unroll
    for (int r = 0; r < 16; ++r, i += 65536) y4[i] = z;
    return;
  }
  if (bid >= 2048) {
    const int r = bid - 2048;           // 0..2047
    const int e = r >> 8;
    const int rr = r & 255;
    const int kt = rr >> 4;             // 0..15
    const int cb = rr & 15;             // 0..15
    wconv2_block(w2 + (size_t)e * HDIM * FDIM, w2b,
                 HDIM, 32, 16, e, kt, cb, (uint32_t*)smem);
    return;
  }
  const int gb = bid;
  const int e  = gb >> 8;
  const int mt = (gb >> 4) & 15;
  const int nt = gb & 15;
  const int cnt = counts[e];
  if (mt * BM >= cnt) return;
  const int off = offsets[e];
  const int tid  = threadIdx.x;
  const int lane = tid & 63;
  const int wid  = tid >> 6;
  const int wr = wid >> 1;
  const int wc = wid & 1;

  u16* A_lds  = (u16*)smem;              // 16 KB, granule^(row&7)
  u16* B1_lds = (u16*)(smem + 16384);    // 8 KB (blob order)
  u16* B3_lds = (u16*)(smem + 24576);    // 8 KB

  const u16* a_src[4];
#pragma unroll
  for (int i = 0; i < 4; ++i) {
    int row = (wid * 4 + i) * 8 + (lane >> 3);
    int mg = mt * BM + row;
    int mc = (mg < cnt) ? mg : (cnt - 1);
    int tok = token_list[off + mc];
    a_src[i] = Xb + (size_t)tok * HDIM + (((lane & 7) ^ (row & 7)) * 8);
  }
  const u16* b1_src[2];
  const u16* b3_src[2];
  {
    size_t tbase = ((size_t)(e * 16 + nt) * 32) * TILE_E;
#pragma unroll
    for (int i = 0; i < 2; ++i) {
      int c = wid * 2 + i;
      b1_src[i] = w1b + tbase + c * 512 + lane * 8;
      b3_src[i] = w3b + tbase + c * 512 + lane * 8;
    }
  }

  f32x16 accg[2] = {};
  f32x16 accu[2] = {};

#pragma unroll
  for (int i = 0; i < 4; ++i) glds16(a_src[i], &A_lds[(wid * 4 + i) * 512]);
#pragma unroll
  for (int i = 0; i < 2; ++i) {
    glds16(b1_src[i], &B1_lds[(wid * 2 + i) * 512]);
    glds16(b3_src[i], &B3_lds[(wid * 2 + i) * 512]);
  }

#pragma unroll 1
  for (int t = 0; t < NK1; ++t) {
    __syncthreads();
    bf16x8 af[2][4], bg[4], bu[4];
#pragma unroll
    for (int m = 0; m < 2; ++m) {
      int R = wr * 64 + m * 32 + (lane & 31);
#pragma unroll
      for (int kk = 0; kk < 4; ++kk) {
        int gl = kk * 2 + (lane >> 5);
        af[m][kk] = *(const bf16x8*)&A_lds[R * BK + ((gl ^ (R & 7)) * 8)];
      }
    }
    {
      int R = wc * 32 + (lane & 31);
      int base = R * 16 + (((lane >> 5) ^ ((R >> 2) & 1)) * 8);
#pragma unroll
      for (int kk = 0; kk < 4; ++kk) {
        bg[kk] = *(const bf16x8*)&B1_lds[base + kk * 1024];
        bu[kk] = *(const bf16x8*)&B3_lds[base + kk * 1024];
      }
    }
    __syncthreads();
    if (t + 1 < NK1) {
      const size_t ks = (size_t)(t + 1) * BK;
      const size_t kb = (size_t)(t + 1) * TILE_E;
#pragma unroll
      for (int i = 0; i < 4; ++i) glds16(a_src[i] + ks, &A_lds[(wid * 4 + i) * 512]);
#pragma unroll
      for (int i = 0; i < 2; ++i) {
        glds16(b1_src[i] + kb, &B1_lds[(wid * 2 + i) * 512]);
        glds16(b3_src[i] + kb, &B3_lds[(wid * 2 + i) * 512]);
      }
    }
#pragma unroll
    for (int m = 0; m < 2; ++m)
#pragma unroll
      for (int kk = 0; kk < 4; ++kk) {
        accg[m] = __builtin_amdgcn_mfma_f32_32x32x16_bf16(af[m][kk], bg[kk], accg[m], 0, 0, 0);
        accu[m] = __builtin_amdgcn_mfma_f32_32x32x16_bf16(af[m][kk], bu[kk], accu[m], 0, 0, 0);
      }
  }

  const int fcol = nt * BN1 + wc * 32 + (lane & 31);
#pragma unroll
  for (int m = 0; m < 2; ++m) {
    int base = mt * BM + wr * 64 + m * 32 + 4 * (lane >> 5);
#pragma unroll
    for (int reg = 0; reg < 16; ++reg) {
      int mg = base + (reg & 3) + 8 * (reg >> 2);
      if (mg < cnt) {
        int slot = off + mg;
        float wgt = slot_w[slot];
        float g = accg[m][reg];
        float u = accu[m][reg];
        float sv = g / (1.f + __expf(-g));
        act[(size_t)slot * FDIM + fcol] = f2bf(sv * u * wgt);
      }
    }
  }
}

// ---------------------------------------------------------------------------
// GEMM2 (unchanged): y += act @ w2 (blob). BM=128 BN=128 BK=64, wave tile
// 64x64, single-buffer 2-barrier schedule, 3 blocks/CU.
// ---------------------------------------------------------------------------
__global__ __launch_bounds__(NTHR, 3)
void gemm2_kernel(const u16* __restrict__ act,
                  const u16* __restrict__ w2b,   // tiled [e][nt32][kt16][4096]
                  const int* __restrict__ token_list,
                  const int* __restrict__ counts,
                  const int* __restrict__ offsets,
                  float* __restrict__ y) {
  const int bid = blockIdx.x;
  const int e  = bid >> 8;
  const int mt = (bid >> 4) & 15;
  const int nt = bid & 15;
  const int cnt = counts[e];
  if (mt * BM >= cnt) return;
  const int off = offsets[e];
  const int tid  = threadIdx.x;
  const int lane = tid & 63;
  const int wid  = tid >> 6;
  const int wr = wid >> 1;
  const int wc = wid & 1;

  __shared__ u16 A_lds[BM * BK];     // 16 KB
  __shared__ u16 B_lds[BN2 * BK];    // 16 KB (two tiles of 4096)

  const u16* a_src[4];
  const u16* b_src[4];
#pragma unroll
  for (int i = 0; i < 4; ++i) {
    int row = (wid * 4 + i) * 8 + (lane >> 3);
    int mg = mt * BM + row;
    int mc = (mg < cnt) ? mg : (cnt - 1);
    a_src[i] = act + (size_t)(off + mc) * FDIM + (((lane & 7) ^ (row & 7)) * 8);
    int c = wid * 4 + i;
    size_t tbase = ((size_t)(e * 32 + nt * 2 + (c >> 3)) * 16) * TILE_E;
    b_src[i] = w2b + tbase + (c & 7) * 512 + lane * 8;
  }

  f32x16 acc[2][2] = {};

#pragma unroll
  for (int i = 0; i < 4; ++i) {
    glds16(a_src[i], &A_lds[(wid * 4 + i) * 512]);
    glds16(b_src[i], &B_lds[(wid * 4 + i) * 512]);
  }

#pragma unroll 1
  for (int t = 0; t < NK2; ++t) {
    __syncthreads();
    bf16x8 af[2][4], bb[2][4];
#pragma unroll
    for (int m = 0; m < 2; ++m) {
      int R = wr * 64 + m * 32 + (lane & 31);
#pragma unroll
      for (int kk = 0; kk < 4; ++kk) {
        int gl = kk * 2 + (lane >> 5);
        af[m][kk] = *(const bf16x8*)&A_lds[R * BK + ((gl ^ (R & 7)) * 8)];
      }
    }
#pragma unroll
    for (int n = 0; n < 2; ++n) {
      int R = wc * 64 + n * 32 + (lane & 31);
      int base = (R >> 6) * TILE_E + (R & 63) * 16 + (((lane >> 5) ^ ((R >> 2) & 1)) * 8);
#pragma unroll
      for (int kk = 0; kk < 4; ++kk)
        bb[n][kk] = *(const bf16x8*)&B_lds[base + kk * 1024];
    }
    __syncthreads();
    if (t + 1 < NK2) {
      const size_t ks = (size_t)(t + 1) * BK;
      const size_t kb = (size_t)(t + 1) * TILE_E;
#pragma unroll
      for (int i = 0; i < 4; ++i) {
        glds16(a_src[i] + ks, &A_lds[(wid * 4 + i) * 512]);
        glds16(b_src[i] + kb, &B_lds[(wid * 4 + i) * 512]);
      }
    }
#pragma unroll
    for (int kk = 0; kk < 4; ++kk)
#pragma unroll
      for (int m = 0; m < 2; ++m)
#pragma unroll
        for (int n = 0; n < 2; ++n)
          acc[m][n] = __builtin_amdgcn_mfma_f32_32x32x16_bf16(af[m][kk], bb[n][kk], acc[m][n], 0, 0, 0);
  }

#pragma unroll
  for (int m = 0; m < 2; ++m) {
    int base = mt * BM + wr * 64 + m * 32 + 4 * (lane >> 5);
#pragma unroll
    for (int reg = 0; reg < 16; ++reg) {
      int mg = base + (reg & 3) + 8 * (reg >> 2);
      if (mg < cnt) {
        int slot = off + mg;
        int tok = token_list[slot];
#pragma unroll
        for (int n = 0; n < 2; ++n) {
          int hcol = nt * BN2 + wc * 64 + n * 32 + (lane & 31);
          unsafeAtomicAdd(y + (size_t)tok * HDIM + hcol, acc[m][n][reg]);
        }
      }
    }
  }
}

// ---------------------------------------------------------------------------
extern "C" void kernel_launch(void* const* d_in, const int* in_sizes, int n_in,
                              void* d_out, int out_size, void* d_ws, size_t ws_size,
                              hipStream_t stream) {
  (void)in_sizes; (void)n_in; (void)out_size; (void)ws_size;
  const float* hs     = (const float*)d_in[0];
  const float* logits = (const float*)d_in[1];
  const float* w1     = (const float*)d_in[2];
  const float* w3     = (const float*)d_in[3];
  const float* w2     = (const float*)d_in[4];
  float* y = (float*)d_out;

  uint8_t* ws = (uint8_t*)d_ws;
  int*   token_list = (int*)(ws);
  float* slot_w     = (float*)(ws + (16 << 10));
  int*   counts     = (int*)(ws + (32 << 10));
  int*   offsets    = (int*)(ws + (32 << 10) + 128);
  int*   cursor     = (int*)(ws + (32 << 10) + 256);
  int*   tok_e      = (int*)(ws + (33 << 10));
  float* tok_w      = (float*)(ws + (42 << 10));
  const size_t MB = 1 << 20;
  u16*   Xb  = (u16*)(ws + (64 << 10));                 // 8 MB
  u16*   act = (u16*)(ws + (64 << 10) + 8 * MB);        // 8 MB
  u16*   w1b = (u16*)(ws + (64 << 10) + 16 * MB);       // 32 MB tiled
  u16*   w3b = (u16*)(ws + (64 << 10) + 48 * MB);       // 32 MB tiled
  u16*   w2b = (u16*)(ws + (64 << 10) + 80 * MB);       // 32 MB tiled

  hipMemsetAsync(counts, 0, NEXP * sizeof(int), stream);
  route1_kernel<<<T_TOK / 256, 256, 0, stream>>>(logits, tok_e, tok_w, counts);
  route2_kernel<<<1, 64, 0, stream>>>(counts, offsets, cursor);
  route3_kernel<<<T_TOK / 256, 256, 0, stream>>>(tok_e, tok_w, cursor, token_list, slot_w);
  mega1_kernel<<<4352, 256, 0, stream>>>(w1, w3, w1b, w3b,
                                         (const float4*)hs, (ushort4*)Xb);
  mega2_kernel<<<4352, 256, 0, stream>>>(w2, w2b, Xb, w1b, w3b,
                                         token_list, slot_w, counts, offsets, act, (float4*)y);
  gemm2_kernel<<<GRID2K, NTHR, 0, stream>>>(act, w2b, token_list, counts, offsets, y);
}